// Round 1
// baseline (1756.626 us; speedup 1.0000x reference)
//
#include <hip/hip_runtime.h>
#include <stdint.h>

#define B_  128
#define G_  360
#define GI_ 174
#define EF_ 512
#define U_  512
#define AU_ 32
#define VOC_ 5000
#define T_  20
#define G4_ 2048

__device__ __forceinline__ float bf2f(unsigned short h){ return __uint_as_float(((unsigned)h)<<16); }
__device__ __forceinline__ unsigned short f2bf(float f){
  unsigned u = __float_as_uint(f);
  u += 0x7fffu + ((u>>16)&1u);
  return (unsigned short)(u>>16);
}
__device__ __forceinline__ float2 bfpair(unsigned u){
  float2 r; r.x = __uint_as_float(u<<16); r.y = __uint_as_float(u & 0xffff0000u); return r;
}
__device__ __forceinline__ float sigmf(float x){ return 1.0f/(1.0f + __expf(-x)); }
__device__ __forceinline__ float tanhf_(float x){ return 1.0f - 2.0f/(1.0f + __expf(2.0f*x)); }
__device__ __forceinline__ float leaky_(float x){ return x >= 0.f ? x : 0.2f*x; }

// ---------------- encoder: feat = LN(leaky(x @ encW[g] + encB[g])) ----------------
// grid (4 b-tiles, 360 g), block 256. feat stored bf16 [B][G][EF].
__global__ __launch_bounds__(256) void k_enc(
    const float* __restrict__ features, const float* __restrict__ encW,
    const float* __restrict__ encB, const float* __restrict__ lng,
    const float* __restrict__ lnb, unsigned short* __restrict__ feat)
{
  __shared__ float xsT[GI_*36];        // [i][b], padded stride 36
  __shared__ unsigned ybf[32*256];     // [bb][tid] packed bf16 pair (pre-LN leaky)
  __shared__ float2 mr[32];
  const int g  = blockIdx.y;
  const int b0 = blockIdx.x * 32;
  const int tid = threadIdx.x;

  for (int idx = tid; idx < 32*GI_; idx += 256) {
    int bb = idx / GI_, i = idx - bb*GI_;
    xsT[i*36 + bb] = features[(size_t)(b0+bb)*(G_*GI_) + (size_t)g*GI_ + i];
  }
  __syncthreads();

  const int e0 = 2*tid;
  float acc0[32], acc1[32];
  #pragma unroll
  for (int bb=0; bb<32; ++bb){ acc0[bb]=0.f; acc1[bb]=0.f; }
  const float* wp = encW + ((size_t)g*GI_)*EF_ + e0;
  for (int i=0;i<GI_;++i){
    float2 w = *(const float2*)(wp); wp += EF_;
    const float* xr = &xsT[i*36];
    #pragma unroll
    for (int bb=0; bb<32; ++bb){
      float xv = xr[bb];
      acc0[bb] += xv*w.x; acc1[bb] += xv*w.y;
    }
  }
  float be0 = encB[(size_t)g*EF_ + e0], be1 = encB[(size_t)g*EF_ + e0 + 1];
  #pragma unroll
  for (int bb=0; bb<32; ++bb){
    float y0 = leaky_(acc0[bb] + be0);
    float y1 = leaky_(acc1[bb] + be1);
    ybf[bb*256 + tid] = ((unsigned)f2bf(y1)<<16) | (unsigned)f2bf(y0);
  }
  __syncthreads();
  // LN stats: wave wv handles rows wv*8 .. wv*8+7
  {
    int wv = tid >> 6, ln = tid & 63;
    #pragma unroll
    for (int q=0;q<8;++q){
      int bb = wv*8 + q;
      uint4 d = ((const uint4*)&ybf[bb*256])[ln];
      float2 p0 = bfpair(d.x), p1 = bfpair(d.y), p2 = bfpair(d.z), p3 = bfpair(d.w);
      float s  = p0.x+p0.y+p1.x+p1.y+p2.x+p2.y+p3.x+p3.y;
      float ss = p0.x*p0.x+p0.y*p0.y+p1.x*p1.x+p1.y*p1.y+p2.x*p2.x+p2.y*p2.y+p3.x*p3.x+p3.y*p3.y;
      #pragma unroll
      for (int mk=1; mk<64; mk<<=1){ s += __shfl_xor(s, mk, 64); ss += __shfl_xor(ss, mk, 64); }
      if (ln == 0){
        float mean = s * (1.f/512.f);
        float var  = ss * (1.f/512.f) - mean*mean;
        mr[bb] = make_float2(mean, rsqrtf(var + 1e-5f));
      }
    }
  }
  __syncthreads();
  float gg0 = lng[e0], gg1 = lng[e0+1], bb0 = lnb[e0], bb1 = lnb[e0+1];
  for (int bb=0; bb<32; ++bb){
    float2 m = mr[bb];
    float2 y = bfpair(ybf[bb*256+tid]);
    float f0 = (y.x - m.x)*m.y*gg0 + bb0;
    float f1v = (y.y - m.x)*m.y*gg1 + bb1;
    ((unsigned*)feat)[((size_t)(b0+bb)*G_ + g)*256 + tid] =
        ((unsigned)f2bf(f1v)<<16) | (unsigned)f2bf(f0);
  }
}

// ---------------- f1 = relu(feat @ attn_W1 + b1), rows = b*G+g ----------------
__global__ __launch_bounds__(256) void k_f1(
    const unsigned short* __restrict__ feat, const float* __restrict__ W1,
    const float* __restrict__ b1, float* __restrict__ f1)
{
  __shared__ unsigned short At[512*64];  // [e][r]
  const int r0 = blockIdx.x * 64;
  const int tid = threadIdx.x;
  {
    int rr = tid >> 2, eb = (tid & 3) * 128;
    const unsigned* src = (const unsigned*)(feat) + (((size_t)(r0+rr)*512 + eb) >> 1);
    for (int k=0;k<64;++k){
      unsigned u = src[k];
      int e = eb + 2*k;
      At[e*64 + rr]     = (unsigned short)(u & 0xffffu);
      At[(e+1)*64 + rr] = (unsigned short)(u >> 16);
    }
  }
  __syncthreads();
  int u = tid & 31, rs = tid >> 5;
  float acc[8];
  #pragma unroll
  for (int i=0;i<8;++i) acc[i]=0.f;
  const float* w1p = W1 + u;
  for (int e=0;e<512;++e){
    float w = w1p[(size_t)e*32];
    uint4 d = *(const uint4*)&At[e*64 + rs*8];
    float2 p0=bfpair(d.x),p1=bfpair(d.y),p2=bfpair(d.z),p3=bfpair(d.w);
    acc[0]+=p0.x*w; acc[1]+=p0.y*w; acc[2]+=p1.x*w; acc[3]+=p1.y*w;
    acc[4]+=p2.x*w; acc[5]+=p2.y*w; acc[6]+=p3.x*w; acc[7]+=p3.y*w;
  }
  float bv = b1[u];
  #pragma unroll
  for (int i=0;i<8;++i){
    float v = acc[i] + bv; v = v>0.f? v:0.f;
    f1[((size_t)(r0 + rs*8 + i))*32 + u] = v;
  }
}

// ---------------- pre[t*128+b][j] = bih[j]+bhh[j] + emb[text[b][t]] @ Wih[:,512:].T ----------------
__global__ __launch_bounds__(256) void k_pre(
    const int* __restrict__ text, const float* __restrict__ emb,
    const float* __restrict__ Wih, const float* __restrict__ bih,
    const float* __restrict__ bhh, float* __restrict__ pre)
{
  __shared__ float As[32*36];
  __shared__ float Ws[64*36];
  __shared__ int idxs[32];
  const int r0 = blockIdx.x * 32;
  const int j0 = blockIdx.y * 64;
  const int tid = threadIdx.x;
  if (tid < 32){
    int r = r0 + tid; int b = r & 127, t = r >> 7;
    idxs[tid] = text[b*T_ + t];
  }
  __syncthreads();
  const int m = tid & 31, bg = tid >> 5;
  float acc[4][2];
  {
    float bj0 = bih[j0+2*m]   + bhh[j0+2*m];
    float bj1 = bih[j0+2*m+1] + bhh[j0+2*m+1];
    #pragma unroll
    for (int i=0;i<4;++i){ acc[i][0]=bj0; acc[i][1]=bj1; }
  }
  const int rrA = tid >> 3, kqA = (tid & 7)*4;
  const int jjW = tid >> 2, kqW = (tid & 3)*8;
  for (int c=0;c<16;++c){
    *(float4*)&As[rrA*36 + kqA] =
        *(const float4*)&emb[(size_t)idxs[rrA]*512 + c*32 + kqA];
    const float* wp = &Wih[(size_t)(j0+jjW)*1024 + 512 + c*32 + kqW];
    *(float4*)&Ws[jjW*36 + kqW]     = *(const float4*)wp;
    *(float4*)&Ws[jjW*36 + kqW + 4] = *(const float4*)(wp+4);
    __syncthreads();
    #pragma unroll
    for (int k4=0;k4<8;++k4){
      float4 w0 = *(const float4*)&Ws[(2*m+0)*36 + k4*4];
      float4 w1 = *(const float4*)&Ws[(2*m+1)*36 + k4*4];
      #pragma unroll
      for (int i=0;i<4;++i){
        float4 a = *(const float4*)&As[(bg*4+i)*36 + k4*4];
        acc[i][0] += a.x*w0.x + a.y*w0.y + a.z*w0.z + a.w*w0.w;
        acc[i][1] += a.x*w1.x + a.y*w1.y + a.z*w1.z + a.w*w1.w;
      }
    }
    __syncthreads();
  }
  #pragma unroll
  for (int i=0;i<4;++i){
    *(float2*)&pre[(size_t)(r0+bg*4+i)*G4_ + j0 + 2*m] = make_float2(acc[i][0], acc[i][1]);
  }
}

// ---------------- per-step gates GEMM, split-K via blockIdx.z ----------------
// z=0: g1 = pre_t + ctx @ Wih[:, :512].T ;  z=1: g2 = a_in @ Whh.T
__global__ __launch_bounds__(256) void k_stepgemm(
    const float* __restrict__ ctx, const float* __restrict__ a_in,
    const float* __restrict__ Wih, const float* __restrict__ Whh,
    const float* __restrict__ pre_t, float* __restrict__ g1,
    float* __restrict__ g2)
{
  __shared__ float As[32*36];
  __shared__ float Ws[64*36];
  const int j0 = blockIdx.x * 64;
  const int r0 = blockIdx.y * 32;
  const int z  = blockIdx.z;
  const float* __restrict__ A = z ? a_in : ctx;
  const float* __restrict__ W = z ? Whh : Wih;
  const int wstride = z ? 512 : 1024;
  float* __restrict__ out = z ? g2 : g1;
  const int tid = threadIdx.x;
  const int m = tid & 31, bg = tid >> 5;
  float acc[4][2];
  if (z == 0){
    #pragma unroll
    for (int i=0;i<4;++i){
      float2 p = *(const float2*)&pre_t[(size_t)(r0+bg*4+i)*G4_ + j0 + 2*m];
      acc[i][0] = p.x; acc[i][1] = p.y;
    }
  } else {
    #pragma unroll
    for (int i=0;i<4;++i){ acc[i][0]=0.f; acc[i][1]=0.f; }
  }
  const int rrA = tid >> 3, kqA = (tid & 7) * 4;
  const int jjW = tid >> 2, kqW = (tid & 3) * 8;
  for (int c=0;c<16;++c){
    *(float4*)&As[rrA*36 + kqA] =
        *(const float4*)&A[(size_t)(r0+rrA)*512 + c*32 + kqA];
    const float* wp = &W[(size_t)(j0+jjW)*wstride + c*32 + kqW];
    *(float4*)&Ws[jjW*36 + kqW]     = *(const float4*)wp;
    *(float4*)&Ws[jjW*36 + kqW + 4] = *(const float4*)(wp+4);
    __syncthreads();
    #pragma unroll
    for (int k4=0;k4<8;++k4){
      float4 w0 = *(const float4*)&Ws[(2*m+0)*36 + k4*4];
      float4 w1 = *(const float4*)&Ws[(2*m+1)*36 + k4*4];
      #pragma unroll
      for (int i=0;i<4;++i){
        float4 a = *(const float4*)&As[(bg*4+i)*36 + k4*4];
        acc[i][0] += a.x*w0.x + a.y*w0.y + a.z*w0.z + a.w*w0.w;
        acc[i][1] += a.x*w1.x + a.y*w1.y + a.z*w1.z + a.w*w1.w;
      }
    }
    __syncthreads();
  }
  #pragma unroll
  for (int i=0;i<4;++i){
    *(float2*)&out[(size_t)(r0+bg*4+i)*G4_ + j0 + 2*m] = make_float2(acc[i][0], acc[i][1]);
  }
}

// ---------------- fused LSTM cell + LN + next-step attention ----------------
// block per b (128 blocks). mode_cell=0: a = a0 (initial attention only).
__global__ __launch_bounds__(256) void k_cellattn(
    const float* __restrict__ g1, const float* __restrict__ g2,
    const float* __restrict__ c_in, float* __restrict__ c_out,
    const float* __restrict__ a0, float* __restrict__ a_out,
    const float* __restrict__ lng, const float* __restrict__ lnb,
    const float* __restrict__ W2, const float* __restrict__ b2,
    const float* __restrict__ Vv, const float* __restrict__ bV,
    const float* __restrict__ f1, const unsigned short* __restrict__ feat,
    float* __restrict__ ctx, float* __restrict__ out_att,
    int mode_cell, int do_attn, int t_att)
{
  __shared__ float a_s[512];
  __shared__ float sc[G_];
  __shared__ float hred[8*32];
  __shared__ float h2s[32];
  __shared__ float red[16];
  __shared__ float mrs[2];
  const int b = blockIdx.x, tid = threadIdx.x;
  const int wv = tid >> 6, ln = tid & 63;

  if (mode_cell){
    float hl2[2];
    #pragma unroll
    for (int q=0;q<2;++q){
      int u = tid + q*256;
      size_t base = (size_t)b*G4_;
      float gi = g1[base+u]      + g2[base+u];
      float gf = g1[base+512+u]  + g2[base+512+u];
      float gc = g1[base+1024+u] + g2[base+1024+u];
      float go = g1[base+1536+u] + g2[base+1536+u];
      float c = sigmf(gf)*c_in[(size_t)b*512+u] + sigmf(gi)*tanhf_(gc);
      c_out[(size_t)b*512+u] = c;
      float h = leaky_(sigmf(go)*tanhf_(c));
      hl2[q] = h;
    }
    float s = hl2[0]+hl2[1], ss = hl2[0]*hl2[0]+hl2[1]*hl2[1];
    #pragma unroll
    for (int mk=1;mk<64;mk<<=1){ s += __shfl_xor(s,mk,64); ss += __shfl_xor(ss,mk,64); }
    if (ln==0){ red[wv]=s; red[8+wv]=ss; }
    __syncthreads();
    if (tid==0){
      float S  = red[0]+red[1]+red[2]+red[3];
      float SS = red[8]+red[9]+red[10]+red[11];
      float mean = S*(1.f/512.f);
      float var  = SS*(1.f/512.f) - mean*mean;
      mrs[0]=mean; mrs[1]=rsqrtf(var+1e-5f);
    }
    __syncthreads();
    float mean = mrs[0], rstd = mrs[1];
    #pragma unroll
    for (int q=0;q<2;++q){
      int u = tid + q*256;
      float av = (hl2[q]-mean)*rstd*lng[u] + lnb[u];
      a_s[u] = av;
      a_out[(size_t)b*512 + u] = av;
    }
  } else {
    a_s[tid]       = a0[(size_t)b*512 + tid];
    a_s[tid+256]   = a0[(size_t)b*512 + tid + 256];
  }
  __syncthreads();
  if (!do_attn) return;

  // h2 = relu(a @ W2 + b2)
  {
    int u = tid & 31, ch = tid >> 5;
    float p = 0.f;
    const float* w2p = W2 + (size_t)ch*64*32 + u;
    const float* ap = a_s + ch*64;
    #pragma unroll 8
    for (int e=0;e<64;++e) p += ap[e]*w2p[(size_t)e*32];
    hred[ch*32+u] = p;
  }
  __syncthreads();
  if (tid < 32){
    float p = hred[tid];
    #pragma unroll
    for (int ch=1; ch<8; ++ch) p += hred[ch*32+tid];
    p += b2[tid];
    h2s[tid] = p>0.f? p:0.f;
  }
  __syncthreads();
  // scores
  float bVv = bV[0];
  for (int gg = tid; gg < G_; gg += 256){
    const float* fp = f1 + ((size_t)b*G_ + gg)*32;
    float s = bVv;
    #pragma unroll
    for (int u=0;u<32;++u) s += tanhf_(fp[u] + h2s[u]) * Vv[u];
    sc[gg] = s;
  }
  __syncthreads();
  // softmax over G
  float mx = -1e30f;
  for (int gg=tid; gg<G_; gg+=256) mx = fmaxf(mx, sc[gg]);
  #pragma unroll
  for (int mk=1;mk<64;mk<<=1) mx = fmaxf(mx, __shfl_xor(mx,mk,64));
  if (ln==0) red[wv]=mx;
  __syncthreads();
  if (tid==0) red[0] = fmaxf(fmaxf(red[0],red[1]),fmaxf(red[2],red[3]));
  __syncthreads();
  mx = red[0];
  float psum = 0.f;
  for (int gg=tid; gg<G_; gg+=256){
    float e = __expf(sc[gg]-mx);
    sc[gg] = e; psum += e;
  }
  #pragma unroll
  for (int mk=1;mk<64;mk<<=1) psum += __shfl_xor(psum,mk,64);
  if (ln==0) red[8+wv]=psum;
  __syncthreads();
  if (tid==0) red[8] = red[8]+red[9]+red[10]+red[11];
  __syncthreads();
  float inv = 1.f/red[8];
  float* wout = out_att + ((size_t)b*T_ + t_att)*G_;
  for (int gg=tid; gg<G_; gg+=256){
    float w = sc[gg]*inv;
    sc[gg] = w;
    wout[gg] = w;
  }
  __syncthreads();
  // ctx = sum_g w[g] * feat[b][g][:]
  {
    const unsigned* fp = (const unsigned*)feat + ((size_t)b*G_)*256 + tid;
    float c0v=0.f, c1v=0.f;
    for (int gg=0; gg<G_; ++gg){
      float2 p = bfpair(fp[(size_t)gg*256]);
      float w = sc[gg];
      c0v += w*p.x; c1v += w*p.y;
    }
    *(float2*)&ctx[(size_t)b*512 + 2*tid] = make_float2(c0v,c1v);
  }
}

// ---------------- decoder layer 1: d1 = leaky(a_all @ dW1 + db1) ----------------
__global__ __launch_bounds__(256) void k_dec1(
    const float* __restrict__ a_all, const float* __restrict__ W1,
    const float* __restrict__ b1, float* __restrict__ d1)
{
  __shared__ float As[32*36];
  __shared__ float Ws[64*36];   // transposed [c][k]
  const int r0 = blockIdx.x*32;
  const int c0 = blockIdx.y*64;
  const int tid = threadIdx.x;
  const int m = tid & 31, bg = tid >> 5;
  float acc[4][2];
  #pragma unroll
  for (int i=0;i<4;++i){ acc[i][0]=0.f; acc[i][1]=0.f; }
  const int rrA = tid>>3, kqA = (tid&7)*4;
  const int kkW = tid>>3, cqW = (tid&7)*8;
  for (int c=0;c<16;++c){
    *(float4*)&As[rrA*36+kqA] =
        *(const float4*)&a_all[(size_t)(r0+rrA)*512 + c*32 + kqA];
    {
      const float* wp = &W1[(size_t)(c*32+kkW)*256 + c0 + cqW];
      float4 v0 = *(const float4*)wp;
      float4 v1 = *(const float4*)(wp+4);
      Ws[(cqW+0)*36+kkW]=v0.x; Ws[(cqW+1)*36+kkW]=v0.y;
      Ws[(cqW+2)*36+kkW]=v0.z; Ws[(cqW+3)*36+kkW]=v0.w;
      Ws[(cqW+4)*36+kkW]=v1.x; Ws[(cqW+5)*36+kkW]=v1.y;
      Ws[(cqW+6)*36+kkW]=v1.z; Ws[(cqW+7)*36+kkW]=v1.w;
    }
    __syncthreads();
    #pragma unroll
    for (int k4=0;k4<8;++k4){
      float4 w0 = *(const float4*)&Ws[(2*m+0)*36 + k4*4];
      float4 w1 = *(const float4*)&Ws[(2*m+1)*36 + k4*4];
      #pragma unroll
      for (int i=0;i<4;++i){
        float4 a = *(const float4*)&As[(bg*4+i)*36 + k4*4];
        acc[i][0] += a.x*w0.x + a.y*w0.y + a.z*w0.z + a.w*w0.w;
        acc[i][1] += a.x*w1.x + a.y*w1.y + a.z*w1.z + a.w*w1.w;
      }
    }
    __syncthreads();
  }
  float bb0 = b1[c0+2*m], bb1 = b1[c0+2*m+1];
  #pragma unroll
  for (int i=0;i<4;++i){
    int r = r0+bg*4+i;
    *(float2*)&d1[(size_t)r*256 + c0 + 2*m] =
        make_float2(leaky_(acc[i][0]+bb0), leaky_(acc[i][1]+bb1));
  }
}

// ---------------- decoder layer 2: logits -> d_out (softmaxed later in place) ----------------
__global__ __launch_bounds__(256) void k_dec2(
    const float* __restrict__ d1, const float* __restrict__ W2,
    const float* __restrict__ b2, float* __restrict__ outp)
{
  __shared__ float As[32*36];
  __shared__ float Ws[64*36];   // transposed [v][k]
  const int r0 = blockIdx.x*32;
  const int v0 = blockIdx.y*64;
  const int tid = threadIdx.x;
  const int m = tid&31, bg = tid>>5;
  float acc[4][2];
  #pragma unroll
  for (int i=0;i<4;++i){ acc[i][0]=0.f; acc[i][1]=0.f; }
  const int rrA = tid>>3, kqA=(tid&7)*4;
  const int kkW = tid>>3, vqW=(tid&7)*8;
  const bool full = (v0 + 64 <= VOC_);
  for (int c=0;c<8;++c){
    *(float4*)&As[rrA*36+kqA] =
        *(const float4*)&d1[(size_t)(r0+rrA)*256 + c*32 + kqA];
    {
      const float* wp = &W2[(size_t)(c*32+kkW)*VOC_ + v0 + vqW];
      if (full){
        float4 v0a = *(const float4*)wp;
        float4 v1a = *(const float4*)(wp+4);
        Ws[(vqW+0)*36+kkW]=v0a.x; Ws[(vqW+1)*36+kkW]=v0a.y;
        Ws[(vqW+2)*36+kkW]=v0a.z; Ws[(vqW+3)*36+kkW]=v0a.w;
        Ws[(vqW+4)*36+kkW]=v1a.x; Ws[(vqW+5)*36+kkW]=v1a.y;
        Ws[(vqW+6)*36+kkW]=v1a.z; Ws[(vqW+7)*36+kkW]=v1a.w;
      } else {
        #pragma unroll
        for (int q=0;q<8;++q){
          int v = v0+vqW+q;
          Ws[(vqW+q)*36+kkW] = (v < VOC_) ? wp[q] : 0.f;
        }
      }
    }
    __syncthreads();
    #pragma unroll
    for (int k4=0;k4<8;++k4){
      float4 w0 = *(const float4*)&Ws[(2*m+0)*36 + k4*4];
      float4 w1 = *(const float4*)&Ws[(2*m+1)*36 + k4*4];
      #pragma unroll
      for (int i=0;i<4;++i){
        float4 a = *(const float4*)&As[(bg*4+i)*36 + k4*4];
        acc[i][0] += a.x*w0.x + a.y*w0.y + a.z*w0.z + a.w*w0.w;
        acc[i][1] += a.x*w1.x + a.y*w1.y + a.z*w1.z + a.w*w1.w;
      }
    }
    __syncthreads();
  }
  int vA = v0 + 2*m;
  if (vA < VOC_){
    float bv0 = b2[vA], bv1 = b2[vA+1];
    #pragma unroll
    for (int i=0;i<4;++i){
      int r = r0+bg*4+i; int b = r&127, t = r>>7;
      size_t orow = ((size_t)b*T_ + t)*VOC_;
      *(float2*)&outp[orow + vA] = make_float2(acc[i][0]+bv0, acc[i][1]+bv1);
    }
  }
}

// ---------------- in-place row softmax over VOC ----------------
__global__ __launch_bounds__(256) void k_softmax(float* __restrict__ outp)
{
  __shared__ float red[8];
  const size_t row = (size_t)blockIdx.x * VOC_;
  const int tid = threadIdx.x;
  const int wv = tid >> 6, ln = tid & 63;
  float v[20];
  float mx = -1e30f;
  #pragma unroll
  for (int k=0;k<20;++k){
    int idx = tid + k*256;
    v[k] = (idx < VOC_) ? outp[row+idx] : -1e30f;
    mx = fmaxf(mx, v[k]);
  }
  #pragma unroll
  for (int mk=1;mk<64;mk<<=1) mx = fmaxf(mx,__shfl_xor(mx,mk,64));
  if (ln==0) red[wv] = mx;
  __syncthreads();
  if (tid==0) red[0]=fmaxf(fmaxf(red[0],red[1]),fmaxf(red[2],red[3]));
  __syncthreads();
  mx = red[0];
  float s=0.f;
  #pragma unroll
  for (int k=0;k<20;++k){ v[k] = __expf(v[k]-mx); s += v[k]; }
  #pragma unroll
  for (int mk=1;mk<64;mk<<=1) s += __shfl_xor(s,mk,64);
  if (ln==0) red[4+wv]=s;
  __syncthreads();
  if (tid==0) red[4]=red[4]+red[5]+red[6]+red[7];
  __syncthreads();
  float inv = 1.f/red[4];
  #pragma unroll
  for (int k=0;k<20;++k){
    int idx = tid + k*256;
    if (idx < VOC_) outp[row+idx] = v[k]*inv;
  }
}

extern "C" void kernel_launch(void* const* d_in, const int* in_sizes, int n_in,
                              void* d_out, int out_size, void* d_ws, size_t ws_size,
                              hipStream_t stream) {
  const float* features = (const float*)d_in[0];
  const int*   text     = (const int*)d_in[1];
  const float* a0    = (const float*)d_in[2];
  const float* c0    = (const float*)d_in[3];
  const float* encW  = (const float*)d_in[4];
  const float* encB  = (const float*)d_in[5];
  const float* encLNg= (const float*)d_in[6];
  const float* encLNb= (const float*)d_in[7];
  const float* attnW1= (const float*)d_in[8];
  const float* attnb1= (const float*)d_in[9];
  const float* attnW2= (const float*)d_in[10];
  const float* attnb2= (const float*)d_in[11];
  const float* attnV = (const float*)d_in[12];
  const float* attnbV= (const float*)d_in[13];
  const float* emb   = (const float*)d_in[14];
  const float* Wih   = (const float*)d_in[15];
  const float* Whh   = (const float*)d_in[16];
  const float* bih   = (const float*)d_in[17];
  const float* bhh   = (const float*)d_in[18];
  const float* lng   = (const float*)d_in[19];
  const float* lnb   = (const float*)d_in[20];
  const float* dW1   = (const float*)d_in[21];
  const float* db1   = (const float*)d_in[22];
  const float* dW2   = (const float*)d_in[23];
  const float* db2   = (const float*)d_in[24];

  uint8_t* w8 = (uint8_t*)d_ws;
  unsigned short* feat = (unsigned short*)w8;            // 47,185,920 B
  float* f1b  = (float*)(w8 + 47185920);                 //  5,898,240 B
  float* pre  = (float*)(w8 + 53084160);                 // 20,971,520 B
  float* ctx  = (float*)(w8 + 74055680);                 //    262,144 B
  float* g1   = (float*)(w8 + 74317824);                 //  1,048,576 B
  float* g2   = (float*)(w8 + 75366400);                 //  1,048,576 B
  float* cws  = (float*)(w8 + 76414976);                 //    262,144 B
  float* a_all= (float*)(w8 + 76677120);                 //  5,242,880 B
  float* d1   = (float*)(w8 + 81920000);                 //  2,621,440 B
  // total ws use: 84,541,440 B

  float* outp = (float*)d_out;
  float* att  = outp + 12800000;   // [B][T][G]

  hipLaunchKernelGGL(k_enc, dim3(4,360), dim3(256), 0, stream,
                     features, encW, encB, encLNg, encLNb, feat);
  hipLaunchKernelGGL(k_f1, dim3(720), dim3(256), 0, stream, feat, attnW1, attnb1, f1b);
  hipLaunchKernelGGL(k_pre, dim3(80,32), dim3(256), 0, stream, text, emb, Wih, bih, bhh, pre);
  // initial attention from a0 -> w_0, ctx_0
  hipLaunchKernelGGL(k_cellattn, dim3(128), dim3(256), 0, stream,
                     g1, g2, c0, cws, a0, a_all, lng, lnb,
                     attnW2, attnb2, attnV, attnbV, f1b, feat, ctx, att,
                     0, 1, 0);
  for (int t=0; t<20; ++t){
    const float* a_in = (t==0) ? a0 : (a_all + (size_t)(t-1)*65536);
    const float* c_in = (t==0) ? c0 : cws;
    hipLaunchKernelGGL(k_stepgemm, dim3(32,4,2), dim3(256), 0, stream,
                       ctx, a_in, Wih, Whh, pre + (size_t)t*262144, g1, g2);
    hipLaunchKernelGGL(k_cellattn, dim3(128), dim3(256), 0, stream,
                       g1, g2, c_in, cws, a0, a_all + (size_t)t*65536, lng, lnb,
                       attnW2, attnb2, attnV, attnbV, f1b, feat, ctx, att,
                       1, (t<19)?1:0, t+1);
  }
  hipLaunchKernelGGL(k_dec1, dim3(80,4), dim3(256), 0, stream, a_all, dW1, db1, d1);
  hipLaunchKernelGGL(k_dec2, dim3(80,79), dim3(256), 0, stream, d1, dW2, db2, outp);
  hipLaunchKernelGGL(k_softmax, dim3(2560), dim3(256), 0, stream, outp);
}

// Round 2
// 1497.886 us; speedup vs baseline: 1.1727x; 1.1727x over previous
//
#include <hip/hip_runtime.h>
#include <stdint.h>

#define B_  128
#define G_  360
#define GI_ 174
#define EF_ 512
#define U_  512
#define AU_ 32
#define VOC_ 5000
#define T_  20

typedef short short8 __attribute__((ext_vector_type(8)));
typedef float floatx4 __attribute__((ext_vector_type(4)));

#define GLD16(gp, lp) __builtin_amdgcn_global_load_lds( \
    (const __attribute__((address_space(1))) void*)(gp), \
    (__attribute__((address_space(3))) void*)(lp), 16, 0, 0)

__device__ __forceinline__ unsigned short f2bf(float f){
  unsigned u = __float_as_uint(f);
  u += 0x7fffu + ((u>>16)&1u);
  return (unsigned short)(u>>16);
}
__device__ __forceinline__ float2 bfpair(unsigned u){
  float2 r; r.x = __uint_as_float(u<<16); r.y = __uint_as_float(u & 0xffff0000u); return r;
}
__device__ __forceinline__ unsigned packbf(float a, float b){
  return ((unsigned)f2bf(b)<<16) | (unsigned)f2bf(a);
}
__device__ __forceinline__ float sigmf(float x){ return 1.0f/(1.0f + __expf(-x)); }
__device__ __forceinline__ float tanhf_(float x){ return 1.0f - 2.0f/(1.0f + __expf(2.0f*x)); }
__device__ __forceinline__ float leaky_(float x){ return x >= 0.f ? x : 0.2f*x; }

// ====================== k_cvt: weight conversion / gather / transpose ==========
__global__ __launch_bounds__(256) void k_cvt(
    const int* __restrict__ text, const float* __restrict__ emb,
    const float* __restrict__ Wih, const float* __restrict__ Whh,
    const float* __restrict__ bih, const float* __restrict__ bhh,
    const float* __restrict__ W1, const float* __restrict__ b1,
    const float* __restrict__ encg, const float* __restrict__ encb,
    const float* __restrict__ dW1, const float* __restrict__ dW2,
    float* __restrict__ stats, unsigned short* __restrict__ Wstep,
    float* __restrict__ bias_sum, unsigned short* __restrict__ ASbuf,
    unsigned short* __restrict__ W1g, float* __restrict__ f1c,
    unsigned short* __restrict__ dW1t, unsigned short* __restrict__ dW2t)
{
  __shared__ float tile[64][65];
  const int blk = blockIdx.x, tid = threadIdx.x;
  if (blk < 90){
    int i = blk*1024 + tid*4;
    *(float4*)&stats[i] = make_float4(0.f,0.f,0.f,0.f);
  } else if (blk < 2138){
    int j = blk - 90;
    #pragma unroll
    for (int q=0;q<6;++q){
      int c = q*256 + tid;
      float v;
      if (c < 512)       v = Wih[(size_t)j*1024 + 512 + c];
      else if (c < 1024) v = Wih[(size_t)j*1024 + (c - 512)];
      else               v = Whh[(size_t)j*512 + (c - 1024)];
      Wstep[(size_t)j*1536 + c] = f2bf(v);
    }
  } else if (blk < 2146){
    int i = (blk-2138)*256 + tid;
    bias_sum[i] = bih[i] + bhh[i];
  } else if (blk < 4706){
    int r = blk - 2146; int t = r >> 7, b = r & 127;
    int idx = text[b*T_ + t];
    float2 v = *(const float2*)&emb[(size_t)idx*512 + 2*tid];
    ((unsigned*)ASbuf)[(((size_t)r*1536)>>1) + tid] = packbf(v.x, v.y);
  } else if (blk == 4706){
    if (tid < 32){
      float gw = 0.f, bw = 0.f;
      for (int k=0;k<512;++k){
        float wv = W1[(size_t)k*32 + tid];
        float gk = encg[k], bk = encb[k];
        W1g[(size_t)tid*512 + k] = f2bf(gk*wv);
        gw += gk*wv; bw += bk*wv;
      }
      f1c[tid] = gw; f1c[32+tid] = bw + b1[tid];
    }
  } else if (blk < 4739){
    int q = blk - 4707; int kt = q >> 2, nt = q & 3;
    int k0 = kt*64, n0 = nt*64;
    #pragma unroll
    for (int it=0; it<16; ++it){
      int idx = it*256 + tid; int kk = idx>>6, nn = idx&63;
      tile[kk][nn] = dW1[(size_t)(k0+kk)*256 + n0+nn];
    }
    __syncthreads();
    #pragma unroll
    for (int it=0; it<16; ++it){
      int idx = it*256 + tid; int nn = idx>>6, kk = idx&63;
      dW1t[(size_t)(n0+nn)*512 + k0+kk] = f2bf(tile[kk][nn]);
    }
  } else {
    int q = blk - 4739; int kt = q/80, nt = q - kt*80;
    int k0 = kt*64, n0 = nt*64;
    #pragma unroll
    for (int it=0; it<16; ++it){
      int idx = it*256 + tid; int kk = idx>>6, nn = idx&63;
      tile[kk][nn] = (n0+nn < VOC_) ? dW2[(size_t)(k0+kk)*VOC_ + n0+nn] : 0.f;
    }
    __syncthreads();
    #pragma unroll
    for (int it=0; it<16; ++it){
      int idx = it*256 + tid; int nn = idx>>6, kk = idx&63;
      dW2t[(size_t)(n0+nn)*256 + k0+kk] = f2bf(tile[kk][nn]);
    }
  }
}

// ====================== k_enc: per-group MFMA GEMM, pre-LN y + stats ==========
__device__ __forceinline__ int swzA(int row, int k){
  return row*192 + ((((k>>3) ^ (row&7)))<<3) + (k&7);
}
__device__ __forceinline__ int swzB(int row, int k){
  return row*64 + ((((k>>3) ^ (row&7)))<<3) + (k&7);
}
__global__ __launch_bounds__(256) void k_enc(
    const float* __restrict__ features, const float* __restrict__ encW,
    const float* __restrict__ encB,
    unsigned short* __restrict__ ybuf, float* __restrict__ stats)
{
  __shared__ __align__(16) unsigned short As[128*192];
  __shared__ __align__(16) unsigned short Bs[128*64];
  const int g = blockIdx.y, n0 = blockIdx.x*128;
  const int tid = threadIdx.x, w = tid>>6, l = tid&63;
  const int quad = l>>4, col16 = l&15;
  const int m0w = (w>>1)*64, n0w = (w&1)*64;

  for (int rr=0; rr<32; ++rr){
    int row = w*32 + rr;
    const float* fp = features + (size_t)row*(G_*GI_) + (size_t)g*GI_;
    float v0 = fp[l];
    float v1 = fp[l+64];
    float v2 = (l < 46) ? fp[l+128] : 0.f;
    As[swzA(row, l)]      = f2bf(v0);
    As[swzA(row, l+64)]   = f2bf(v1);
    As[swzA(row, l+128)]  = f2bf(v2);
  }

  floatx4 acc[4][4];
  #pragma unroll
  for (int mi=0;mi<4;++mi)
    #pragma unroll
    for (int ni=0;ni<4;++ni)
      acc[mi][ni] = (floatx4){0.f,0.f,0.f,0.f};

  for (int c=0; c<3; ++c){
    if (c > 0) __syncthreads();
    int kc0 = c*64;
    #pragma unroll
    for (int z=0; z<16; ++z){
      int k = kc0 + w + 4*z;
      int kk = w + 4*z;
      if (k < GI_){
        const float* wp = encW + ((size_t)g*GI_ + k)*512 + n0;
        Bs[swzB(l,    kk)] = f2bf(wp[l]);
        Bs[swzB(l+64, kk)] = f2bf(wp[l+64]);
      } else {
        Bs[swzB(l,    kk)] = 0;
        Bs[swzB(l+64, kk)] = 0;
      }
    }
    __syncthreads();
    #pragma unroll
    for (int it=0; it<2; ++it){
      int kg = c*64 + it*32 + quad*8;
      int kk = it*32 + quad*8;
      short8 af[4], bfr[4];
      #pragma unroll
      for (int mi=0;mi<4;++mi){
        int row = m0w + mi*16 + col16;
        af[mi] = *(const short8*)&As[row*192 + (((kg>>3) ^ (row&7))<<3)];
      }
      #pragma unroll
      for (int ni=0;ni<4;++ni){
        int rowb = n0w + ni*16 + col16;
        bfr[ni] = *(const short8*)&Bs[rowb*64 + (((kk>>3) ^ (rowb&7))<<3)];
      }
      #pragma unroll
      for (int mi=0;mi<4;++mi)
        #pragma unroll
        for (int ni=0;ni<4;++ni)
          acc[mi][ni] = __builtin_amdgcn_mfma_f32_16x16x32_bf16(af[mi], bfr[ni], acc[mi][ni], 0,0,0);
    }
  }

  #pragma unroll
  for (int mi=0;mi<4;++mi){
    float sy[4] = {0.f,0.f,0.f,0.f};
    float sq[4] = {0.f,0.f,0.f,0.f};
    #pragma unroll
    for (int ni=0;ni<4;++ni){
      int nG = n0 + n0w + ni*16 + col16;
      float bv = encB[(size_t)g*512 + nG];
      #pragma unroll
      for (int reg=0;reg<4;++reg){
        int row = m0w + mi*16 + quad*4 + reg;
        float y = leaky_(acc[mi][ni][reg] + bv);
        unsigned short yh = f2bf(y);
        ybuf[((size_t)row*G_ + g)*512 + nG] = yh;
        float yr = __uint_as_float(((unsigned)yh)<<16);
        sy[reg] += yr; sq[reg] += yr*yr;
      }
    }
    #pragma unroll
    for (int reg=0; reg<4; ++reg){
      float a = sy[reg], bq = sq[reg];
      #pragma unroll
      for (int mk=1; mk<16; mk<<=1){ a += __shfl_xor(a, mk, 64); bq += __shfl_xor(bq, mk, 64); }
      if (col16 == 0){
        int row = m0w + mi*16 + quad*4 + reg;
        atomicAdd(&stats[((size_t)row*G_ + g)*2],     a);
        atomicAdd(&stats[((size_t)row*G_ + g)*2 + 1], bq);
      }
    }
  }
}

// ====================== generic bf16 MFMA GEMM (A[M][K], Bt[N][K]) ==========
template<int TN, int NBK, int MODE>
__global__ __launch_bounds__(256) void k_gemm(
    const unsigned short* __restrict__ A, int lda,
    const unsigned short* __restrict__ Bt, int ldb,
    const float* __restrict__ bias,
    float* __restrict__ outf, unsigned short* __restrict__ outh,
    const float* __restrict__ stats, float* __restrict__ stats2,
    const float* __restrict__ f1c)
{
  constexpr int NI = TN/32;
  __shared__ __align__(16) unsigned short As[128*64];
  __shared__ __align__(16) unsigned short Bs[TN*64];
  const int tid = threadIdx.x;
  const int w = tid >> 6, l = tid & 63;
  const int n0 = blockIdx.x * TN;
  const int r0 = blockIdx.y * 128;
  const int quad = l>>4, col16 = l&15;
  const int m0w = (w>>1)*64, n0w = (w&1)*(TN/2);
  const int arow = w*32, brow = w*(TN/4);

  const unsigned short* Ag = A + (size_t)(r0 + arow + (l>>3))*lda + (l&7)*8;
  const unsigned short* Bg = Bt + (size_t)(n0 + brow + (l>>3))*ldb + (l&7)*8;

  floatx4 acc[4][NI];
  #pragma unroll
  for (int mi=0;mi<4;++mi)
    #pragma unroll
    for (int ni=0;ni<NI;++ni)
      acc[mi][ni] = (floatx4){0.f,0.f,0.f,0.f};

  for (int it=0; it<NBK; ++it){
    int k0 = it*64;
    #pragma unroll
    for (int q=0;q<4;++q)
      GLD16(Ag + (size_t)q*8*lda + k0, As + (arow + q*8)*64);
    #pragma unroll
    for (int q=0;q<TN/32;++q)
      GLD16(Bg + (size_t)q*8*ldb + k0, Bs + (brow + q*8)*64);
    __syncthreads();
    #pragma unroll
    for (int kc=0;kc<2;++kc){
      int koff = kc*32 + quad*8;
      short8 af[4], bfr[NI];
      #pragma unroll
      for (int mi=0;mi<4;++mi)
        af[mi] = *(const short8*)&As[(m0w + mi*16 + col16)*64 + koff];
      #pragma unroll
      for (int ni=0;ni<NI;++ni)
        bfr[ni] = *(const short8*)&Bs[(n0w + ni*16 + col16)*64 + koff];
      #pragma unroll
      for (int mi=0;mi<4;++mi)
        #pragma unroll
        for (int ni=0;ni<NI;++ni)
          acc[mi][ni] = __builtin_amdgcn_mfma_f32_16x16x32_bf16(af[mi], bfr[ni], acc[mi][ni], 0,0,0);
    }
    __syncthreads();
  }

  if constexpr (MODE == 0){
    #pragma unroll
    for (int ni=0; ni<NI; ++ni){
      int nG = n0 + n0w + ni*16 + col16;
      float bv = bias[nG];
      #pragma unroll
      for (int mi=0; mi<4; ++mi)
        #pragma unroll
        for (int reg=0; reg<4; ++reg){
          int r = r0 + m0w + mi*16 + quad*4 + reg;
          outf[(size_t)r*2048 + nG] = acc[mi][ni][reg] + bv;
        }
    }
  } else if constexpr (MODE == 1){
    int nG = n0w + col16;
    float gw = f1c[nG], bwv = f1c[32+nG];
    #pragma unroll
    for (int mi=0; mi<4; ++mi)
      #pragma unroll
      for (int reg=0; reg<4; ++reg){
        int r = r0 + m0w + mi*16 + quad*4 + reg;
        float2 st = *(const float2*)&stats[(size_t)r*2];
        float m = st.x * (1.f/512.f);
        float var = st.y * (1.f/512.f) - m*m;
        float rs = rsqrtf(var + 1e-5f);
        float v = rs*(acc[mi][0][reg] - m*gw) + bwv;
        v = v > 0.f ? v : 0.f;
        outf[(size_t)r*32 + nG] = v;
        if (((w&1)==0) && col16==0){
          stats2[(size_t)r*2] = m; stats2[(size_t)r*2+1] = rs;
        }
      }
  } else if constexpr (MODE == 2){
    #pragma unroll
    for (int ni=0; ni<NI; ++ni){
      int nG = n0 + n0w + ni*16 + col16;
      float bv = bias[nG];
      #pragma unroll
      for (int mi=0; mi<4; ++mi)
        #pragma unroll
        for (int reg=0; reg<4; ++reg){
          int r = r0 + m0w + mi*16 + quad*4 + reg;
          outh[(size_t)r*256 + nG] = f2bf(leaky_(acc[mi][ni][reg] + bv));
        }
    }
  } else {
    #pragma unroll
    for (int ni=0; ni<NI; ++ni){
      int nG = n0 + n0w + ni*16 + col16;
      if (nG < VOC_){
        float bv = bias[nG];
        #pragma unroll
        for (int mi=0; mi<4; ++mi)
          #pragma unroll
          for (int reg=0; reg<4; ++reg){
            int r = r0 + m0w + mi*16 + quad*4 + reg;
            int bb = r & 127, tt = r >> 7;
            outf[((size_t)bb*T_ + tt)*VOC_ + nG] = acc[mi][ni][reg] + bv;
          }
      }
    }
  }
}

// ====================== fused LSTM cell + LN + next-step attention ==========
__global__ __launch_bounds__(256) void k_cellattn(
    const float* __restrict__ g, const float* __restrict__ c_in,
    float* __restrict__ c_out, const float* __restrict__ a0,
    const float* __restrict__ lng, const float* __restrict__ lnb,
    const float* __restrict__ W2, const float* __restrict__ b2,
    const float* __restrict__ Vv, const float* __restrict__ bV,
    const float* __restrict__ f1, const unsigned short* __restrict__ ybuf,
    const float* __restrict__ stats2,
    const float* __restrict__ encg, const float* __restrict__ encb,
    unsigned short* __restrict__ ASlot, unsigned short* __restrict__ a_bf,
    float* __restrict__ att_out, int t_att, int mode_cell, int do_attn)
{
  __shared__ float a_s[512];
  __shared__ float sc[G_];
  __shared__ float hred[8*32];
  __shared__ float h2s[32];
  __shared__ float red[16];
  __shared__ float mrs[2];
  const int b = blockIdx.x, tid = threadIdx.x;
  const int wv = tid >> 6, ln = tid & 63;

  if (mode_cell){
    float hl2[2];
    #pragma unroll
    for (int q=0;q<2;++q){
      int u = tid + q*256;
      size_t base = (size_t)b*2048;
      float gi = g[base+u];
      float gf = g[base+512+u];
      float gc = g[base+1024+u];
      float go = g[base+1536+u];
      float c = sigmf(gf)*c_in[(size_t)b*512+u] + sigmf(gi)*tanhf_(gc);
      c_out[(size_t)b*512+u] = c;
      hl2[q] = leaky_(sigmf(go)*tanhf_(c));
    }
    float s = hl2[0]+hl2[1], ss = hl2[0]*hl2[0]+hl2[1]*hl2[1];
    #pragma unroll
    for (int mk=1;mk<64;mk<<=1){ s += __shfl_xor(s,mk,64); ss += __shfl_xor(ss,mk,64); }
    if (ln==0){ red[wv]=s; red[8+wv]=ss; }
    __syncthreads();
    if (tid==0){
      float S  = red[0]+red[1]+red[2]+red[3];
      float SS = red[8]+red[9]+red[10]+red[11];
      float mean = S*(1.f/512.f);
      float var  = SS*(1.f/512.f) - mean*mean;
      mrs[0]=mean; mrs[1]=rsqrtf(var+1e-5f);
    }
    __syncthreads();
    float mean = mrs[0], rstd = mrs[1];
    #pragma unroll
    for (int q=0;q<2;++q){
      int u = tid + q*256;
      float av = (hl2[q]-mean)*rstd*lng[u] + lnb[u];
      a_s[u] = av;
      a_bf[(size_t)b*512 + u] = f2bf(av);
      if (do_attn) ASlot[(size_t)b*1536 + 1024 + u] = f2bf(av);
    }
  } else {
    #pragma unroll
    for (int q=0;q<2;++q){
      int u = tid + q*256;
      float av = a0[(size_t)b*512 + u];
      a_s[u] = av;
      ASlot[(size_t)b*1536 + 1024 + u] = f2bf(av);
    }
  }
  __syncthreads();
  if (!do_attn) return;

  {
    int u = tid & 31, ch = tid >> 5;
    float p = 0.f;
    const float* w2p = W2 + (size_t)ch*64*32 + u;
    const float* ap = a_s + ch*64;
    #pragma unroll 8
    for (int e=0;e<64;++e) p += ap[e]*w2p[(size_t)e*32];
    hred[ch*32+u] = p;
  }
  __syncthreads();
  if (tid < 32){
    float p = hred[tid];
    #pragma unroll
    for (int ch=1; ch<8; ++ch) p += hred[ch*32+tid];
    p += b2[tid];
    h2s[tid] = p>0.f? p:0.f;
  }
  __syncthreads();
  float bVv = bV[0];
  for (int gg = tid; gg < G_; gg += 256){
    const float* fp = f1 + ((size_t)b*G_ + gg)*32;
    float s = bVv;
    #pragma unroll
    for (int u=0;u<32;++u) s += tanhf_(fp[u] + h2s[u]) * Vv[u];
    sc[gg] = s;
  }
  __syncthreads();
  float mx = -1e30f;
  for (int gg=tid; gg<G_; gg+=256) mx = fmaxf(mx, sc[gg]);
  #pragma unroll
  for (int mk=1;mk<64;mk<<=1) mx = fmaxf(mx, __shfl_xor(mx,mk,64));
  if (ln==0) red[wv]=mx;
  __syncthreads();
  if (tid==0) red[0] = fmaxf(fmaxf(red[0],red[1]),fmaxf(red[2],red[3]));
  __syncthreads();
  mx = red[0];
  float psum = 0.f;
  for (int gg=tid; gg<G_; gg+=256){
    float e = __expf(sc[gg]-mx);
    sc[gg] = e; psum += e;
  }
  #pragma unroll
  for (int mk=1;mk<64;mk<<=1) psum += __shfl_xor(psum,mk,64);
  if (ln==0) red[8+wv]=psum;
  __syncthreads();
  if (tid==0) red[8] = red[8]+red[9]+red[10]+red[11];
  __syncthreads();
  float inv = 1.f/red[8];
  float Mop = 0.f;
  float* wout = att_out + ((size_t)b*T_ + t_att)*G_;
  for (int gg=tid; gg<G_; gg+=256){
    float wg = sc[gg]*inv;
    wout[gg] = wg;
    float2 st = *(const float2*)&stats2[((size_t)b*G_+gg)*2];
    sc[gg] = wg*st.y;
    Mop += wg*st.x*st.y;
  }
  #pragma unroll
  for (int mk=1;mk<64;mk<<=1) Mop += __shfl_xor(Mop,mk,64);
  if (ln==0) red[4+wv] = Mop;
  __syncthreads();
  if (tid==0) mrs[0] = red[4]+red[5]+red[6]+red[7];
  __syncthreads();
  float Mo = mrs[0];
  {
    const unsigned* fp = (const unsigned*)ybuf + ((size_t)b*G_)*256 + tid;
    float c0v=0.f, c1v=0.f;
    for (int gg=0; gg<G_; ++gg){
      float2 p = bfpair(fp[(size_t)gg*256]);
      float wq = sc[gg];
      c0v += wq*p.x; c1v += wq*p.y;
    }
    int e0 = 2*tid;
    float ctx0 = encg[e0]  *(c0v - Mo) + encb[e0];
    float ctx1 = encg[e0+1]*(c1v - Mo) + encb[e0+1];
    ((unsigned*)ASlot)[(((size_t)b*1536 + 512)>>1) + tid] = packbf(ctx0, ctx1);
  }
}

// ====================== in-place row softmax over VOC ==========
__global__ __launch_bounds__(256) void k_softmax(float* __restrict__ outp)
{
  __shared__ float red[8];
  const size_t row = (size_t)blockIdx.x * VOC_;
  const int tid = threadIdx.x;
  const int wv = tid >> 6, ln = tid & 63;
  float v[20];
  float mx = -1e30f;
  #pragma unroll
  for (int k=0;k<20;++k){
    int idx = tid + k*256;
    v[k] = (idx < VOC_) ? outp[row+idx] : -1e30f;
    mx = fmaxf(mx, v[k]);
  }
  #pragma unroll
  for (int mk=1;mk<64;mk<<=1) mx = fmaxf(mx,__shfl_xor(mx,mk,64));
  if (ln==0) red[wv] = mx;
  __syncthreads();
  if (tid==0) red[0]=fmaxf(fmaxf(red[0],red[1]),fmaxf(red[2],red[3]));
  __syncthreads();
  mx = red[0];
  float s=0.f;
  #pragma unroll
  for (int k=0;k<20;++k){ v[k] = __expf(v[k]-mx); s += v[k]; }
  #pragma unroll
  for (int mk=1;mk<64;mk<<=1) s += __shfl_xor(s,mk,64);
  if (ln==0) red[4+wv]=s;
  __syncthreads();
  if (tid==0) red[4]=red[4]+red[5]+red[6]+red[7];
  __syncthreads();
  float inv = 1.f/red[4];
  #pragma unroll
  for (int k=0;k<20;++k){
    int idx = tid + k*256;
    if (idx < VOC_) outp[row+idx] = v[k]*inv;
  }
}

extern "C" void kernel_launch(void* const* d_in, const int* in_sizes, int n_in,
                              void* d_out, int out_size, void* d_ws, size_t ws_size,
                              hipStream_t stream) {
  const float* features = (const float*)d_in[0];
  const int*   text     = (const int*)d_in[1];
  const float* a0    = (const float*)d_in[2];
  const float* c0    = (const float*)d_in[3];
  const float* encW  = (const float*)d_in[4];
  const float* encB  = (const float*)d_in[5];
  const float* encLNg= (const float*)d_in[6];
  const float* encLNb= (const float*)d_in[7];
  const float* attnW1= (const float*)d_in[8];
  const float* attnb1= (const float*)d_in[9];
  const float* attnW2= (const float*)d_in[10];
  const float* attnb2= (const float*)d_in[11];
  const float* attnV = (const float*)d_in[12];
  const float* attnbV= (const float*)d_in[13];
  const float* emb   = (const float*)d_in[14];
  const float* Wih   = (const float*)d_in[15];
  const float* Whh   = (const float*)d_in[16];
  const float* bih   = (const float*)d_in[17];
  const float* bhh   = (const float*)d_in[18];
  const float* lng   = (const float*)d_in[19];
  const float* lnb   = (const float*)d_in[20];
  const float* dW1   = (const float*)d_in[21];
  const float* db1   = (const float*)d_in[22];
  const float* dW2   = (const float*)d_in[23];
  const float* db2   = (const float*)d_in[24];

  uint8_t* w8 = (uint8_t*)d_ws;
  unsigned short* ybuf   = (unsigned short*)(w8);              // 47,185,920
  float*          stats  = (float*)(w8 + 47185920);            //    368,640
  float*          stats2 = (float*)(w8 + 47554560);            //    368,640
  float*          f1b    = (float*)(w8 + 47923200);            //  5,898,240
  unsigned short* ASbuf  = (unsigned short*)(w8 + 53821440);   //  7,864,320
  unsigned short* Wstep  = (unsigned short*)(w8 + 61685760);   //  6,291,456
  float*          bias_sum=(float*)(w8 + 67977216);            //      8,192
  unsigned short* W1g    = (unsigned short*)(w8 + 67985408);   //     32,768
  float*          f1c    = (float*)(w8 + 68018176);            //        256
  unsigned short* dW1t   = (unsigned short*)(w8 + 68018432);   //    262,144
  unsigned short* dW2t   = (unsigned short*)(w8 + 68280576);   //  2,621,440
  float*          gbuf   = (float*)(w8 + 70902016);            //  1,048,576
  float*          cws    = (float*)(w8 + 71950592);            //    262,144
  unsigned short* a_bf   = (unsigned short*)(w8 + 72212736);   //  2,621,440
  unsigned short* d1bf   = (unsigned short*)(w8 + 74834176);   //  1,310,720

  float* outp = (float*)d_out;
  float* att  = outp + 12800000;   // [B][T][G]

  hipLaunchKernelGGL(k_cvt, dim3(5059), dim3(256), 0, stream,
                     text, emb, Wih, Whh, bih, bhh, attnW1, attnb1,
                     encLNg, encLNb, dW1, dW2,
                     stats, Wstep, bias_sum, ASbuf, W1g, f1c, dW1t, dW2t);
  hipLaunchKernelGGL(k_enc, dim3(4,360), dim3(256), 0, stream,
                     features, encW, encB, ybuf, stats);
  hipLaunchKernelGGL((k_gemm<32,8,1>), dim3(1,360), dim3(256), 0, stream,
                     ybuf, 512, W1g, 512, (const float*)nullptr,
                     f1b, (unsigned short*)nullptr, stats, stats2, f1c);
  hipLaunchKernelGGL(k_cellattn, dim3(128), dim3(256), 0, stream,
                     gbuf, c0, cws, a0, lng, lnb, attnW2, attnb2, attnV, attnbV,
                     f1b, ybuf, stats2, encLNg, encLNb,
                     ASbuf, a_bf, att, 0, 0, 1);
  for (int t=0; t<T_; ++t){
    hipLaunchKernelGGL((k_gemm<64,24,0>), dim3(32,1), dim3(256), 0, stream,
                       ASbuf + (size_t)t*128*1536, 1536, Wstep, 1536, bias_sum,
                       gbuf, (unsigned short*)nullptr,
                       (const float*)nullptr, (float*)nullptr, (const float*)nullptr);
    int da = (t < T_-1) ? 1 : 0;
    unsigned short* slot = ASbuf + (size_t)((t+1 < T_) ? (t+1) : 0)*128*1536;
    hipLaunchKernelGGL(k_cellattn, dim3(128), dim3(256), 0, stream,
                       gbuf, (t==0)?c0:cws, cws, a0, lng, lnb,
                       attnW2, attnb2, attnV, attnbV,
                       f1b, ybuf, stats2, encLNg, encLNb,
                       slot, a_bf + (size_t)t*128*512, att, t+1, 1, da);
  }
  hipLaunchKernelGGL((k_gemm<128,8,2>), dim3(2,20), dim3(256), 0, stream,
                     a_bf, 512, dW1t, 512, db1,
                     (float*)nullptr, d1bf, (const float*)nullptr, (float*)nullptr,
                     (const float*)nullptr);
  hipLaunchKernelGGL((k_gemm<128,4,3>), dim3(40,20), dim3(256), 0, stream,
                     d1bf, 256, dW2t, 256, db2,
                     outp, (unsigned short*)nullptr, (const float*)nullptr,
                     (float*)nullptr, (const float*)nullptr);
  hipLaunchKernelGGL(k_softmax, dim3(2560), dim3(256), 0, stream, outp);
}